// Round 3
// baseline (725.542 us; speedup 1.0000x reference)
//
#include <hip/hip_runtime.h>
#include <math.h>

static constexpr int S  = 2048;
static constexpr int D  = 64;
static constexpr int BH = 32;   // B*H = 2*16

typedef __bf16 bf16;
typedef __bf16 bf16x8 __attribute__((ext_vector_type(8)));
typedef float  f32x4  __attribute__((ext_vector_type(4)));

__device__ __forceinline__ int swz(int row, int chunk) { return chunk ^ (row & 7); }

__device__ __forceinline__ f32x4 mfma16(bf16x8 a, bf16x8 b, f32x4 c) {
    return __builtin_amdgcn_mfma_f32_16x16x32_bf16(a, b, c, 0, 0, 0);
}

// async global->LDS, 16B per lane; LDS dest is wave-uniform base + lane*16
__device__ __forceinline__ void gl16(const bf16* g, bf16* l) {
    __builtin_amdgcn_global_load_lds(
        (const __attribute__((address_space(1))) void*)g,
        (__attribute__((address_space(3))) void*)l,
        16, 0, 0);
}

// Stage a Rx64 fp32 tile (row stride 64) into LDS as bf16, XOR-swizzled chunks.
template <int NCHUNK>
__device__ __forceinline__ void stage_rowmajor(const float* __restrict__ src,
                                               bf16* dst, int tid) {
#pragma unroll
    for (int id = tid; id < NCHUNK; id += 512) {
        const int row = id >> 3;
        const int c   = id & 7;
        const float4* p = (const float4*)(src + row * 64 + c * 8);
        float4 a = p[0], b = p[1];
        bf16x8 v;
        v[0] = (bf16)a.x; v[1] = (bf16)a.y; v[2] = (bf16)a.z; v[3] = (bf16)a.w;
        v[4] = (bf16)b.x; v[5] = (bf16)b.y; v[6] = (bf16)b.z; v[7] = (bf16)b.w;
        *(bf16x8*)(dst + row * 64 + swz(row, c) * 8) = v;
    }
}

// ---------------------------------------------------------------------------
// P0a: bit-pack masks [2][S][S] int32 -> [2][S][S/32] u32 (1 MiB, L2-resident)
// ---------------------------------------------------------------------------
__global__ __launch_bounds__(256) void p0_bitpack(const int* __restrict__ masks,
                                                  unsigned* __restrict__ mbits) {
    const int idx = blockIdx.x * 256 + threadIdx.x;   // (b*S+s)*64 + w
    const int4* p = (const int4*)(masks + (size_t)idx * 32);
    unsigned word = 0;
#pragma unroll
    for (int i = 0; i < 8; ++i) {
        int4 m = p[i];
        word |= (m.x != 0 ? 1u : 0u) << (i * 4 + 0);
        word |= (m.y != 0 ? 1u : 0u) << (i * 4 + 1);
        word |= (m.z != 0 ? 1u : 0u) << (i * 4 + 2);
        word |= (m.w != 0 ? 1u : 0u) << (i * 4 + 3);
    }
    mbits[idx] = word;
}

// ---------------------------------------------------------------------------
// P0b: K -> bf16 tiled+swizzled image; V -> transposed bf16 tiled+swizzled
// image Vt[d][t]. Blocks [0,1024) do K, [1024,2048) V.
// ---------------------------------------------------------------------------
__global__ __launch_bounds__(256) void p0_kvimg(const float* __restrict__ ksrc,
                                                const float* __restrict__ vsrc,
                                                bf16* __restrict__ kimg,
                                                bf16* __restrict__ vimg) {
    __shared__ float Vf[64 * 65];
    const int tid = threadIdx.x;
    if (blockIdx.x < 1024) {                       // ---- K path ----
        const int tile = blockIdx.x;
        const float* sbase = ksrc + (size_t)tile * 4096;
        bf16* dbase = kimg + (size_t)tile * 4096;
#pragma unroll
        for (int u = 0; u < 2; ++u) {
            const int id  = tid + u * 256;
            const int row = id >> 3;
            const int c   = id & 7;
            const float4* p = (const float4*)(sbase + row * 64 + c * 8);
            float4 a = p[0], b = p[1];
            bf16x8 v;
            v[0] = (bf16)a.x; v[1] = (bf16)a.y; v[2] = (bf16)a.z; v[3] = (bf16)a.w;
            v[4] = (bf16)b.x; v[5] = (bf16)b.y; v[6] = (bf16)b.z; v[7] = (bf16)b.w;
            *(bf16x8*)(dbase + row * 64 + swz(row, c) * 8) = v;
        }
    } else {                                       // ---- V transpose path ----
        const int tile = blockIdx.x - 1024;
        const float* sbase = vsrc + (size_t)tile * 4096;
        bf16* dbase = vimg + (size_t)tile * 4096;
#pragma unroll
        for (int u = 0; u < 2; ++u) {
            const int id  = tid + u * 256;
            const int row = id >> 3;            // t
            const int c   = id & 7;
            const float4* p = (const float4*)(sbase + row * 64 + c * 8);
            float4 a = p[0], b = p[1];
            float* d = Vf + row * 65 + c * 8;
            d[0] = a.x; d[1] = a.y; d[2] = a.z; d[3] = a.w;
            d[4] = b.x; d[5] = b.y; d[6] = b.z; d[7] = b.w;
        }
        __syncthreads();
#pragma unroll
        for (int u = 0; u < 2; ++u) {
            const int id = tid + u * 256;
            const int dd = id >> 3;             // d
            const int c  = id & 7;              // t chunk
            bf16x8 v;
#pragma unroll
            for (int j = 0; j < 8; ++j) v[j] = (bf16)Vf[(c * 8 + j) * 65 + dd];
            *(bf16x8*)(dbase + dd * 64 + swz(dd, c) * 8) = v;
        }
    }
}

// ---------------------------------------------------------------------------
// P1: out = (masked scaled scores) @ V   [MFMA, faithful bug: raw scores]
// Also dumps the bf16 masked scores (Simg) into the upper 64 KiB of each
// strip's attn output region, as coalesced 16B/lane tiles (zero extra VALU:
// the aS registers already hold the strip in exactly this layout).
// No softmax stats here anymore -- p2_stream derives them from Simg.
// ---------------------------------------------------------------------------
__global__ __launch_bounds__(512) void p1_out(
    const float* __restrict__ q, const bf16* __restrict__ Kimg,
    const bf16* __restrict__ Vimg, const unsigned* __restrict__ mbits,
    float* __restrict__ out, float* __restrict__ attn) {
    __shared__ __align__(16) bf16 QSb[128 * 64];   // Q (prologue) -> Sb[8][16*64]
    __shared__ __align__(16) bf16 KB[2][64 * 64];
    __shared__ __align__(16) bf16 VB[2][64 * 64];

    const int bh   = blockIdx.y;
    const int s0   = blockIdx.x * 128;
    const int b    = bh >> 4;
    const int tid  = threadIdx.x;
    const int w    = tid >> 6;
    const int lane = tid & 63;
    const int col  = lane & 15;
    const int quad = lane >> 4;

    const bf16* kt_base = Kimg + (size_t)bh * 32 * 4096;
    const bf16* vt_base = Vimg + (size_t)bh * 32 * 4096;
    const int soff = tid * 8;          // per-lane source element offset (16B/lane)
    const int doff = w * 512;          // wave-uniform LDS dest element offset

    stage_rowmajor<1024>(q + ((size_t)bh * S + s0) * D, QSb, tid);
    gl16(kt_base + soff, &KB[0][doff]);
    gl16(vt_base + soff, &VB[0][doff]);
    __syncthreads();   // Q + tile 0 resident

    const int ar = w * 16 + col;               // A-operand row (m = lane&15)
    bf16x8 aQ0 = *(bf16x8*)(QSb + ar * 64 + swz(ar, quad) * 8);
    bf16x8 aQ1 = *(bf16x8*)(QSb + ar * 64 + swz(ar, 4 + quad) * 8);
    __syncthreads();   // all waves hold aQ in regs; QSb now reusable as Sb

    bf16* Sbw = QSb + w * 1024;        // wave-private 16x64 strip

    // Simg destination: upper 64 KiB of this strip's attn region.
    // Strip rows = s0 + w*16 .. +16; region byte base = rowFloatBase*4; + 65536.
    const size_t stripFloatBase = ((size_t)bh * S + s0 + w * 16) * (size_t)S;
    bf16* Sg = (bf16*)((char*)attn + stripFloatBase * 4 + 65536);
    const int slot0 = quad ^ (col & 7);
    const int slot1 = (4 + quad) ^ (col & 7);
    bf16* Sg0 = Sg + col * 64 + slot0 * 8;     // row col, stored slot0 (16B)
    bf16* Sg1 = Sg + col * 64 + slot1 * 8;

    f32x4 oacc[4] = {};

    const unsigned* mrow[4];
#pragma unroll
    for (int r = 0; r < 4; ++r)
        mrow[r] = mbits + (size_t)(b * S + s0 + w * 16 + quad * 4 + r) * 64;

    int cur = 0;
    for (int kt = 0; kt < 32; ++kt) {
        unsigned mw[4][2];
#pragma unroll
        for (int r = 0; r < 4; ++r) {
            mw[r][0] = mrow[r][kt * 2 + 0];
            mw[r][1] = mrow[r][kt * 2 + 1];
        }

        // prefetch next tile into the other buffer (overlaps with compute below)
        if (kt < 31) {
            gl16(kt_base + (size_t)(kt + 1) * 4096 + soff, &KB[cur ^ 1][doff]);
            gl16(vt_base + (size_t)(kt + 1) * 4096 + soff, &VB[cur ^ 1][doff]);
        }

        const bf16* Kc = KB[cur];
        const bf16* Vc = VB[cur];

        // ---- QK^T, mask+scale, stash S (bf16) in A-layout strip ----
#pragma unroll
        for (int ct = 0; ct < 4; ++ct) {
            const int br = ct * 16 + col;      // K row (t)
            bf16x8 b0 = *(bf16x8*)(Kc + br * 64 + swz(br, quad) * 8);
            bf16x8 b1 = *(bf16x8*)(Kc + br * 64 + swz(br, 4 + quad) * 8);
            __builtin_amdgcn_s_setprio(1);
            f32x4 s = {};
            s = mfma16(aQ0, b0, s);
            s = mfma16(aQ1, b1, s);
            __builtin_amdgcn_s_setprio(0);
            const int t   = ct * 16 + col;
            const int pos = t & 31;
#pragma unroll
            for (int r = 0; r < 4; ++r) {
                const float sv = ((mw[r][ct >> 1] >> pos) & 1u)
                                     ? s[r] * 0.125f : -1e-12f;
                const int sr = quad * 4 + r;   // C-layout row within strip
                Sbw[sr * 64 + swz(sr, t >> 3) * 8 + (t & 7)] = (bf16)sv;
            }
        }

        // ---- load A-fragments of S; dump them to Simg (coalesced 16B/lane) ----
        bf16x8 aS0 = *(bf16x8*)(Sbw + col * 64 + swz(col, quad) * 8);
        bf16x8 aS1 = *(bf16x8*)(Sbw + col * 64 + swz(col, 4 + quad) * 8);
        *(bf16x8*)(Sg0 + kt * 1024) = aS0;     // fire-and-forget
        *(bf16x8*)(Sg1 + kt * 1024) = aS1;

        // ---- out += S @ V (wave-private strip) ----
        __builtin_amdgcn_s_setprio(1);
#pragma unroll
        for (int dt = 0; dt < 4; ++dt) {
            const int vr = dt * 16 + col;      // Vt row (d)
            bf16x8 b0 = *(bf16x8*)(Vc + vr * 64 + swz(vr, quad) * 8);
            bf16x8 b1 = *(bf16x8*)(Vc + vr * 64 + swz(vr, 4 + quad) * 8);
            oacc[dt] = mfma16(aS0, b0, oacc[dt]);
            oacc[dt] = mfma16(aS1, b1, oacc[dt]);
        }
        __builtin_amdgcn_s_setprio(0);

        __syncthreads();   // next tile resident; all waves done reading cur
        cur ^= 1;
    }

    // ---- epilogue: out rows (s0 + w*16 + quad*4 + r), cols (dt*16 + col) ----
    float* ob = out + ((size_t)bh * S + s0 + w * 16 + quad * 4) * D;
#pragma unroll
    for (int dt = 0; dt < 4; ++dt)
#pragma unroll
        for (int r = 0; r < 4; ++r)
            ob[(size_t)r * D + dt * 16 + col] = oacc[dt][r];
}

// ---------------------------------------------------------------------------
// P2: pure stream. One block per 16-row strip: read the strip's bf16 Simg
// (64 KiB, in-place in the upper half of the strip's own output region),
// compute per-row sum of exp, then write attn = exp(sv)/rowsum as f32
// (128 KiB, full 256B segments). In-place safe: all reads land in registers
// before the barrier; writes only after it; cross-block regions disjoint.
// ---------------------------------------------------------------------------
__global__ __launch_bounds__(512) void p2_stream(float* __restrict__ attn) {
    __shared__ float lsum[512];
    __shared__ float linv_s[16];
    const int strip = blockIdx.x;             // bh*128 + rstrip
    const int tid = threadIdx.x;
    const int sr  = (tid & 127) >> 3;         // row within strip (const per thread)
    const int c   = tid & 7;                  // stored chunk slot
    const int tc  = c ^ (sr & 7);             // actual t-chunk
    const int kb  = tid >> 7;                 // kt offset 0..3

    const size_t rowbase = (size_t)strip * 16 * 2048;   // float idx of strip row 0
    const bf16* in = (const bf16*)((const char*)attn + rowbase * 4 + 65536);
    const int ioff = (tid & 127) * 8;         // in-tile element offset (= sr*64+c*8)

    bf16x8 vin[8];
#pragma unroll
    for (int i = 0; i < 8; ++i)
        vin[i] = *(const bf16x8*)(in + (size_t)(i * 4 + kb) * 1024 + ioff);

    float partial = 0.f;
#pragma unroll
    for (int i = 0; i < 8; ++i)
#pragma unroll
        for (int j = 0; j < 8; ++j)
            partial += __expf((float)vin[i][j]);

    lsum[tid] = partial;
    __syncthreads();
    if (tid < 16) {
        float s = 0.f;
#pragma unroll
        for (int p = 0; p < 4; ++p)
#pragma unroll
            for (int cc = 0; cc < 8; ++cc)
                s += lsum[p * 128 + tid * 8 + cc];
        linv_s[tid] = 1.0f / s;
    }
    __syncthreads();
    const float li = linv_s[sr];

    float* orow = attn + rowbase + (size_t)sr * 2048 + tc * 8;
#pragma unroll
    for (int i = 0; i < 8; ++i) {
        const int kt = i * 4 + kb;
        float4 f0, f1;
        f0.x = __expf((float)vin[i][0]) * li;
        f0.y = __expf((float)vin[i][1]) * li;
        f0.z = __expf((float)vin[i][2]) * li;
        f0.w = __expf((float)vin[i][3]) * li;
        f1.x = __expf((float)vin[i][4]) * li;
        f1.y = __expf((float)vin[i][5]) * li;
        f1.z = __expf((float)vin[i][6]) * li;
        f1.w = __expf((float)vin[i][7]) * li;
        *(float4*)(orow + kt * 64)     = f0;
        *(float4*)(orow + kt * 64 + 4) = f1;
    }
}

extern "C" void kernel_launch(void* const* d_in, const int* in_sizes, int n_in,
                              void* d_out, int out_size, void* d_ws, size_t ws_size,
                              hipStream_t stream) {
    const float* q     = (const float*)d_in[0];
    const float* k     = (const float*)d_in[1];
    const float* v     = (const float*)d_in[2];
    const int*   masks = (const int*)d_in[3];

    float* out  = (float*)d_out;                 // [2,16,S,D]
    float* attn = out + (size_t)BH * S * D;      // [2,16,S,S]

    // workspace layout (17.25 MiB):
    //   [0, 1 MiB)            mbits
    //   [1 MiB, +256 KiB)     (spare)
    //   [1.25 MiB, +8 MiB)    Kimg  (bf16 tiled+swizzled)
    //   [9.25 MiB, +8 MiB)    Vimg  (bf16 transposed tiled+swizzled)
    unsigned* mbits = (unsigned*)d_ws;
    bf16*     Kimg  = (bf16*)((char*)d_ws + (size_t)1048576 + 262144);
    bf16*     Vimg  = (bf16*)((char*)d_ws + (size_t)1048576 + 262144 + 8388608);

    p0_bitpack<<<(2 * S * 64) / 256, 256, 0, stream>>>(masks, mbits);
    p0_kvimg<<<2048, 256, 0, stream>>>(k, v, Kimg, Vimg);

    dim3 g(S / 128, BH);   // x = row-tile (consecutive blocks share bh -> L2 locality)
    p1_out<<<g, 512, 0, stream>>>(q, Kimg, Vimg, mbits, out, attn);
    p2_stream<<<BH * (S / 16), 512, 0, stream>>>(attn);
}

// Round 4
// 713.854 us; speedup vs baseline: 1.0164x; 1.0164x over previous
//
#include <hip/hip_runtime.h>
#include <math.h>

static constexpr int S  = 2048;
static constexpr int D  = 64;
static constexpr int BH = 32;   // B*H = 2*16

typedef __bf16 bf16;
typedef __bf16 bf16x8 __attribute__((ext_vector_type(8)));
typedef float  f32x4  __attribute__((ext_vector_type(4)));

__device__ __forceinline__ int swz(int row, int chunk) { return chunk ^ (row & 7); }

__device__ __forceinline__ f32x4 mfma16(bf16x8 a, bf16x8 b, f32x4 c) {
    return __builtin_amdgcn_mfma_f32_16x16x32_bf16(a, b, c, 0, 0, 0);
}

// async global->LDS, 16B per lane; LDS dest is wave-uniform base + lane*16
__device__ __forceinline__ void gl16(const bf16* g, bf16* l) {
    __builtin_amdgcn_global_load_lds(
        (const __attribute__((address_space(1))) void*)g,
        (__attribute__((address_space(3))) void*)l,
        16, 0, 0);
}

// Stage a Rx64 fp32 tile (row stride 64) into LDS as bf16, XOR-swizzled chunks.
template <int NCHUNK>
__device__ __forceinline__ void stage_rowmajor(const float* __restrict__ src,
                                               bf16* dst, int tid) {
#pragma unroll
    for (int id = tid; id < NCHUNK; id += 512) {
        const int row = id >> 3;
        const int c   = id & 7;
        const float4* p = (const float4*)(src + row * 64 + c * 8);
        float4 a = p[0], b = p[1];
        bf16x8 v;
        v[0] = (bf16)a.x; v[1] = (bf16)a.y; v[2] = (bf16)a.z; v[3] = (bf16)a.w;
        v[4] = (bf16)b.x; v[5] = (bf16)b.y; v[6] = (bf16)b.z; v[7] = (bf16)b.w;
        *(bf16x8*)(dst + row * 64 + swz(row, c) * 8) = v;
    }
}

// ---------------------------------------------------------------------------
// P0a: bit-pack masks [2][S][S] int32 -> [2][S][S/32] u32 (1 MiB, L2-resident)
// ---------------------------------------------------------------------------
__global__ __launch_bounds__(256) void p0_bitpack(const int* __restrict__ masks,
                                                  unsigned* __restrict__ mbits) {
    const int idx = blockIdx.x * 256 + threadIdx.x;   // (b*S+s)*64 + w
    const int4* p = (const int4*)(masks + (size_t)idx * 32);
    unsigned word = 0;
#pragma unroll
    for (int i = 0; i < 8; ++i) {
        int4 m = p[i];
        word |= (m.x != 0 ? 1u : 0u) << (i * 4 + 0);
        word |= (m.y != 0 ? 1u : 0u) << (i * 4 + 1);
        word |= (m.z != 0 ? 1u : 0u) << (i * 4 + 2);
        word |= (m.w != 0 ? 1u : 0u) << (i * 4 + 3);
    }
    mbits[idx] = word;
}

// ---------------------------------------------------------------------------
// P0b: K -> bf16 tiled+swizzled image; V -> transposed bf16 tiled+swizzled
// image Vt[d][t]. Blocks [0,1024) do K, [1024,2048) V.
// ---------------------------------------------------------------------------
__global__ __launch_bounds__(256) void p0_kvimg(const float* __restrict__ ksrc,
                                                const float* __restrict__ vsrc,
                                                bf16* __restrict__ kimg,
                                                bf16* __restrict__ vimg) {
    __shared__ float Vf[64 * 65];
    const int tid = threadIdx.x;
    if (blockIdx.x < 1024) {                       // ---- K path ----
        const int tile = blockIdx.x;
        const float* sbase = ksrc + (size_t)tile * 4096;
        bf16* dbase = kimg + (size_t)tile * 4096;
#pragma unroll
        for (int u = 0; u < 2; ++u) {
            const int id  = tid + u * 256;
            const int row = id >> 3;
            const int c   = id & 7;
            const float4* p = (const float4*)(sbase + row * 64 + c * 8);
            float4 a = p[0], b = p[1];
            bf16x8 v;
            v[0] = (bf16)a.x; v[1] = (bf16)a.y; v[2] = (bf16)a.z; v[3] = (bf16)a.w;
            v[4] = (bf16)b.x; v[5] = (bf16)b.y; v[6] = (bf16)b.z; v[7] = (bf16)b.w;
            *(bf16x8*)(dbase + row * 64 + swz(row, c) * 8) = v;
        }
    } else {                                       // ---- V transpose path ----
        const int tile = blockIdx.x - 1024;
        const float* sbase = vsrc + (size_t)tile * 4096;
        bf16* dbase = vimg + (size_t)tile * 4096;
#pragma unroll
        for (int u = 0; u < 2; ++u) {
            const int id  = tid + u * 256;
            const int row = id >> 3;            // t
            const int c   = id & 7;
            const float4* p = (const float4*)(sbase + row * 64 + c * 8);
            float4 a = p[0], b = p[1];
            float* d = Vf + row * 65 + c * 8;
            d[0] = a.x; d[1] = a.y; d[2] = a.z; d[3] = a.w;
            d[4] = b.x; d[5] = b.y; d[6] = b.z; d[7] = b.w;
        }
        __syncthreads();
#pragma unroll
        for (int u = 0; u < 2; ++u) {
            const int id = tid + u * 256;
            const int dd = id >> 3;             // d
            const int c  = id & 7;              // t chunk
            bf16x8 v;
#pragma unroll
            for (int j = 0; j < 8; ++j) v[j] = (bf16)Vf[(c * 8 + j) * 65 + dd];
            *(bf16x8*)(dbase + dd * 64 + swz(dd, c) * 8) = v;
        }
    }
}

// ---------------------------------------------------------------------------
// P1 (fused, single main kernel):
//   pass 1: QK^T -> mask -> bf16 stash -> PV accumulate; rowsum of exp(bf16 s)
//   write out; compute linv per row (wave-private LDS broadcast)
//   pass 2: re-stage K (L2-hot, 512 KiB/bh), recompute identical scores,
//           write attn = exp(s)*linv as f32, 4 coalesced float4 stores/thread/kt
// No intermediate global buffers, no extra kernels.
// ---------------------------------------------------------------------------
__global__ __launch_bounds__(512) void p1_fused(
    const float* __restrict__ q, const bf16* __restrict__ Kimg,
    const bf16* __restrict__ Vimg, const unsigned* __restrict__ mbits,
    float* __restrict__ out, float* __restrict__ attn) {
    __shared__ __align__(16) bf16 QSb[128 * 64];   // Q (prologue) -> Sb[8][16*64]
    __shared__ __align__(16) bf16 KB[2][64 * 64];
    __shared__ __align__(16) bf16 VB[2][64 * 64];
    __shared__ float linv_sh[8][16];

    const int bh   = blockIdx.y;
    const int s0   = blockIdx.x * 128;
    const int b    = bh >> 4;
    const int tid  = threadIdx.x;
    const int w    = tid >> 6;
    const int lane = tid & 63;
    const int col  = lane & 15;
    const int quad = lane >> 4;

    const bf16* kt_base = Kimg + (size_t)bh * 32 * 4096;
    const bf16* vt_base = Vimg + (size_t)bh * 32 * 4096;
    const int soff = tid * 8;          // per-lane source element offset (16B/lane)
    const int doff = w * 512;          // wave-uniform LDS dest element offset

    stage_rowmajor<1024>(q + ((size_t)bh * S + s0) * D, QSb, tid);
    gl16(kt_base + soff, &KB[0][doff]);
    gl16(vt_base + soff, &VB[0][doff]);
    __syncthreads();   // Q + tile 0 resident

    const int ar = w * 16 + col;               // A-operand row (m = lane&15)
    bf16x8 aQ0 = *(bf16x8*)(QSb + ar * 64 + swz(ar, quad) * 8);
    bf16x8 aQ1 = *(bf16x8*)(QSb + ar * 64 + swz(ar, 4 + quad) * 8);
    __syncthreads();   // all waves hold aQ in regs; QSb now reusable as Sb

    bf16* Sbw = QSb + w * 1024;        // wave-private 16x64 strip

    f32x4 oacc[4] = {};
    float l[4] = {0.f, 0.f, 0.f, 0.f};

    const unsigned* mrow[4];
#pragma unroll
    for (int r = 0; r < 4; ++r)
        mrow[r] = mbits + (size_t)(b * S + s0 + w * 16 + quad * 4 + r) * 64;

    // ======================= pass 1: out + row sums =======================
    int cur = 0;
    for (int kt = 0; kt < 32; ++kt) {
        unsigned mw[4][2];
#pragma unroll
        for (int r = 0; r < 4; ++r) {
            mw[r][0] = mrow[r][kt * 2 + 0];
            mw[r][1] = mrow[r][kt * 2 + 1];
        }

        if (kt < 31) {
            gl16(kt_base + (size_t)(kt + 1) * 4096 + soff, &KB[cur ^ 1][doff]);
            gl16(vt_base + (size_t)(kt + 1) * 4096 + soff, &VB[cur ^ 1][doff]);
        }

        const bf16* Kc = KB[cur];
        const bf16* Vc = VB[cur];

#pragma unroll
        for (int ct = 0; ct < 4; ++ct) {
            const int br = ct * 16 + col;      // K row (t)
            bf16x8 b0 = *(bf16x8*)(Kc + br * 64 + swz(br, quad) * 8);
            bf16x8 b1 = *(bf16x8*)(Kc + br * 64 + swz(br, 4 + quad) * 8);
            __builtin_amdgcn_s_setprio(1);
            f32x4 s = {};
            s = mfma16(aQ0, b0, s);
            s = mfma16(aQ1, b1, s);
            __builtin_amdgcn_s_setprio(0);
            const int t   = ct * 16 + col;
            const int pos = t & 31;
#pragma unroll
            for (int r = 0; r < 4; ++r) {
                const float sv = ((mw[r][ct >> 1] >> pos) & 1u)
                                     ? s[r] * 0.125f : -1e-12f;
                const bf16 bsv = (bf16)sv;
                l[r] += __expf((float)bsv);    // sum over bf16-rounded (matches pass 2)
                const int sr = quad * 4 + r;   // C-layout row within strip
                Sbw[sr * 64 + swz(sr, t >> 3) * 8 + (t & 7)] = bsv;
            }
        }

        bf16x8 aS0 = *(bf16x8*)(Sbw + col * 64 + swz(col, quad) * 8);
        bf16x8 aS1 = *(bf16x8*)(Sbw + col * 64 + swz(col, 4 + quad) * 8);
        __builtin_amdgcn_s_setprio(1);
#pragma unroll
        for (int dt = 0; dt < 4; ++dt) {
            const int vr = dt * 16 + col;      // Vt row (d)
            bf16x8 b0 = *(bf16x8*)(Vc + vr * 64 + swz(vr, quad) * 8);
            bf16x8 b1 = *(bf16x8*)(Vc + vr * 64 + swz(vr, 4 + quad) * 8);
            oacc[dt] = mfma16(aS0, b0, oacc[dt]);
            oacc[dt] = mfma16(aS1, b1, oacc[dt]);
        }
        __builtin_amdgcn_s_setprio(0);

        __syncthreads();
        cur ^= 1;
    }

    // ---- out epilogue: rows (s0 + w*16 + quad*4 + r), cols (dt*16 + col) ----
    float* ob = out + ((size_t)bh * S + s0 + w * 16 + quad * 4) * D;
#pragma unroll
    for (int dt = 0; dt < 4; ++dt)
#pragma unroll
        for (int r = 0; r < 4; ++r)
            ob[(size_t)r * D + dt * 16 + col] = oacc[dt][r];

    // ---- row-sum reduce across the 16 col-lanes; broadcast linv via LDS ----
#pragma unroll
    for (int r = 0; r < 4; ++r) {
        float x = l[r];
        x += __shfl_xor(x, 1, 16);
        x += __shfl_xor(x, 2, 16);
        x += __shfl_xor(x, 4, 16);
        x += __shfl_xor(x, 8, 16);
        if (col == 0) linv_sh[w][quad * 4 + r] = 1.0f / x;
    }
    // re-prime K tile 0 for pass 2 (cur is back to 0 after 32 flips)
    gl16(kt_base + soff, &KB[0][doff]);
    __syncthreads();   // linv_sh visible (wave-private anyway) + K0 resident
    const float li = linv_sh[w][col];  // lane's A-layout row = col

    // ======================= pass 2: attn writes ==========================
    // attn row for this lane's A-fragment: s0 + w*16 + col
    float* arow = attn + ((size_t)bh * S + s0 + w * 16 + col) * (size_t)S;

    cur = 0;
    for (int kt = 0; kt < 32; ++kt) {
        unsigned mw[4][2];
#pragma unroll
        for (int r = 0; r < 4; ++r) {
            mw[r][0] = mrow[r][kt * 2 + 0];
            mw[r][1] = mrow[r][kt * 2 + 1];
        }

        if (kt < 31)
            gl16(kt_base + (size_t)(kt + 1) * 4096 + soff, &KB[cur ^ 1][doff]);

        const bf16* Kc = KB[cur];

#pragma unroll
        for (int ct = 0; ct < 4; ++ct) {
            const int br = ct * 16 + col;
            bf16x8 b0 = *(bf16x8*)(Kc + br * 64 + swz(br, quad) * 8);
            bf16x8 b1 = *(bf16x8*)(Kc + br * 64 + swz(br, 4 + quad) * 8);
            __builtin_amdgcn_s_setprio(1);
            f32x4 s = {};
            s = mfma16(aQ0, b0, s);
            s = mfma16(aQ1, b1, s);
            __builtin_amdgcn_s_setprio(0);
            const int t   = ct * 16 + col;
            const int pos = t & 31;
#pragma unroll
            for (int r = 0; r < 4; ++r) {
                const float sv = ((mw[r][ct >> 1] >> pos) & 1u)
                                     ? s[r] * 0.125f : -1e-12f;
                const int sr = quad * 4 + r;
                Sbw[sr * 64 + swz(sr, t >> 3) * 8 + (t & 7)] = (bf16)sv;
            }
        }

        // A-fragment readback: lane holds row `col`, t = quad*8..+8 (aS0)
        // and t = 32+quad*8..+8 (aS1). exp*linv, 4 coalesced float4 stores.
        bf16x8 aS0 = *(bf16x8*)(Sbw + col * 64 + swz(col, quad) * 8);
        bf16x8 aS1 = *(bf16x8*)(Sbw + col * 64 + swz(col, 4 + quad) * 8);
        float e[16];
#pragma unroll
        for (int j = 0; j < 8; ++j) {
            e[j]     = __expf((float)aS0[j]) * li;
            e[8 + j] = __expf((float)aS1[j]) * li;
        }
        float* p0 = arow + kt * 64 + quad * 8;
        float* p1 = arow + kt * 64 + 32 + quad * 8;
        *(float4*)(p0)     = make_float4(e[0], e[1], e[2], e[3]);
        *(float4*)(p0 + 4) = make_float4(e[4], e[5], e[6], e[7]);
        *(float4*)(p1)     = make_float4(e[8], e[9], e[10], e[11]);
        *(float4*)(p1 + 4) = make_float4(e[12], e[13], e[14], e[15]);

        __syncthreads();
        cur ^= 1;
    }
}

extern "C" void kernel_launch(void* const* d_in, const int* in_sizes, int n_in,
                              void* d_out, int out_size, void* d_ws, size_t ws_size,
                              hipStream_t stream) {
    const float* q     = (const float*)d_in[0];
    const float* k     = (const float*)d_in[1];
    const float* v     = (const float*)d_in[2];
    const int*   masks = (const int*)d_in[3];

    float* out  = (float*)d_out;                 // [2,16,S,D]
    float* attn = out + (size_t)BH * S * D;      // [2,16,S,S]

    // workspace layout (17.25 MiB):
    //   [0, 1 MiB)            mbits
    //   [1 MiB, +256 KiB)     (spare)
    //   [1.25 MiB, +8 MiB)    Kimg  (bf16 tiled+swizzled)
    //   [9.25 MiB, +8 MiB)    Vimg  (bf16 transposed tiled+swizzled)
    unsigned* mbits = (unsigned*)d_ws;
    bf16*     Kimg  = (bf16*)((char*)d_ws + (size_t)1048576 + 262144);
    bf16*     Vimg  = (bf16*)((char*)d_ws + (size_t)1048576 + 262144 + 8388608);

    p0_bitpack<<<(2 * S * 64) / 256, 256, 0, stream>>>(masks, mbits);
    p0_kvimg<<<2048, 256, 0, stream>>>(k, v, Kimg, Vimg);

    dim3 g(S / 128, BH);   // x = row-tile (consecutive blocks share bh -> L2 locality)
    p1_fused<<<g, 512, 0, stream>>>(q, Kimg, Vimg, mbits, out, attn);
}

// Round 5
// 711.350 us; speedup vs baseline: 1.0200x; 1.0035x over previous
//
#include <hip/hip_runtime.h>
#include <math.h>

static constexpr int S  = 2048;
static constexpr int D  = 64;
static constexpr int BH = 32;   // B*H = 2*16

typedef __bf16 bf16;
typedef __bf16 bf16x8 __attribute__((ext_vector_type(8)));
typedef float  f32x4  __attribute__((ext_vector_type(4)));

__device__ __forceinline__ int swz(int row, int chunk) { return chunk ^ (row & 7); }

__device__ __forceinline__ f32x4 mfma16(bf16x8 a, bf16x8 b, f32x4 c) {
    return __builtin_amdgcn_mfma_f32_16x16x32_bf16(a, b, c, 0, 0, 0);
}

// async global->LDS, 16B per lane; LDS dest is wave-uniform base + lane*16
__device__ __forceinline__ void gl16(const bf16* g, bf16* l) {
    __builtin_amdgcn_global_load_lds(
        (const __attribute__((address_space(1))) void*)g,
        (__attribute__((address_space(3))) void*)l,
        16, 0, 0);
}

// Stage a Rx64 fp32 tile (row stride 64) into LDS as bf16, XOR-swizzled chunks.
template <int NCHUNK>
__device__ __forceinline__ void stage_rowmajor(const float* __restrict__ src,
                                               bf16* dst, int tid) {
#pragma unroll
    for (int id = tid; id < NCHUNK; id += 512) {
        const int row = id >> 3;
        const int c   = id & 7;
        const float4* p = (const float4*)(src + row * 64 + c * 8);
        float4 a = p[0], b = p[1];
        bf16x8 v;
        v[0] = (bf16)a.x; v[1] = (bf16)a.y; v[2] = (bf16)a.z; v[3] = (bf16)a.w;
        v[4] = (bf16)b.x; v[5] = (bf16)b.y; v[6] = (bf16)b.z; v[7] = (bf16)b.w;
        *(bf16x8*)(dst + row * 64 + swz(row, c) * 8) = v;
    }
}

// k-axis permutation baked into the Vt image so that the swapped-QK^T output
// registers ARE the PV A-fragment: slot p (within a 32-t block, quad q=p>>3,
// j=p&7) must hold t = q*4+j (j<4) or 16+q*4+(j-4) (j>=4).
__device__ __forceinline__ int tau(int p) {
    const int hi = p & 32;
    const int q  = (p & 31) >> 3;
    const int j  = p & 7;
    return hi + ((j < 4) ? q * 4 + j : 16 + q * 4 + (j - 4));
}

// ---------------------------------------------------------------------------
// P0a: bit-pack masks [2][S][S] int32 -> [2][S][S/32] u32 (1 MiB, L2-resident)
// ---------------------------------------------------------------------------
__global__ __launch_bounds__(256) void p0_bitpack(const int* __restrict__ masks,
                                                  unsigned* __restrict__ mbits) {
    const int idx = blockIdx.x * 256 + threadIdx.x;   // (b*S+s)*64 + w
    const int4* p = (const int4*)(masks + (size_t)idx * 32);
    unsigned word = 0;
#pragma unroll
    for (int i = 0; i < 8; ++i) {
        int4 m = p[i];
        word |= (m.x != 0 ? 1u : 0u) << (i * 4 + 0);
        word |= (m.y != 0 ? 1u : 0u) << (i * 4 + 1);
        word |= (m.z != 0 ? 1u : 0u) << (i * 4 + 2);
        word |= (m.w != 0 ? 1u : 0u) << (i * 4 + 3);
    }
    mbits[idx] = word;
}

// ---------------------------------------------------------------------------
// P0b: K -> bf16 tiled+swizzled image; V -> transposed bf16 tiled+swizzled
// image Vt[d][t_pos] with t_pos permuted by tau (PV fragment order).
// Blocks [0,1024) do K, [1024,2048) V.
// ---------------------------------------------------------------------------
__global__ __launch_bounds__(256) void p0_kvimg(const float* __restrict__ ksrc,
                                                const float* __restrict__ vsrc,
                                                bf16* __restrict__ kimg,
                                                bf16* __restrict__ vimg) {
    __shared__ float Vf[64 * 65];
    const int tid = threadIdx.x;
    if (blockIdx.x < 1024) {                       // ---- K path ----
        const int tile = blockIdx.x;
        const float* sbase = ksrc + (size_t)tile * 4096;
        bf16* dbase = kimg + (size_t)tile * 4096;
#pragma unroll
        for (int u = 0; u < 2; ++u) {
            const int id  = tid + u * 256;
            const int row = id >> 3;
            const int c   = id & 7;
            const float4* p = (const float4*)(sbase + row * 64 + c * 8);
            float4 a = p[0], b = p[1];
            bf16x8 v;
            v[0] = (bf16)a.x; v[1] = (bf16)a.y; v[2] = (bf16)a.z; v[3] = (bf16)a.w;
            v[4] = (bf16)b.x; v[5] = (bf16)b.y; v[6] = (bf16)b.z; v[7] = (bf16)b.w;
            *(bf16x8*)(dbase + row * 64 + swz(row, c) * 8) = v;
        }
    } else {                                       // ---- V transpose path ----
        const int tile = blockIdx.x - 1024;
        const float* sbase = vsrc + (size_t)tile * 4096;
        bf16* dbase = vimg + (size_t)tile * 4096;
#pragma unroll
        for (int u = 0; u < 2; ++u) {
            const int id  = tid + u * 256;
            const int row = id >> 3;            // t
            const int c   = id & 7;
            const float4* p = (const float4*)(sbase + row * 64 + c * 8);
            float4 a = p[0], b = p[1];
            float* d = Vf + row * 65 + c * 8;
            d[0] = a.x; d[1] = a.y; d[2] = a.z; d[3] = a.w;
            d[4] = b.x; d[5] = b.y; d[6] = b.z; d[7] = b.w;
        }
        __syncthreads();
#pragma unroll
        for (int u = 0; u < 2; ++u) {
            const int id = tid + u * 256;
            const int dd = id >> 3;             // d
            const int c  = id & 7;              // t_pos chunk
            bf16x8 v;
#pragma unroll
            for (int j = 0; j < 8; ++j)
                v[j] = (bf16)Vf[tau(c * 8 + j) * 65 + dd];
            *(bf16x8*)(dbase + dd * 64 + swz(dd, c) * 8) = v;
        }
    }
}

// ---------------------------------------------------------------------------
// P1 (fused, swapped-operand QK^T):
//   mfma(K_frag, Q_frag) -> lane (col,quad) holds s for q-row=col,
//   t = ct*16 + quad*4 + r. The PV A-fragment is assembled IN-LANE (no LDS
//   stash/readback); the implied k-permutation is baked into the Vt image.
//   pass 1: scores -> mask -> pack bf16 A-frag -> PV accumulate; lsum of exp
//   pass 2: recompute scores (K re-staged, L2-hot), write attn = exp*li (f32).
// ---------------------------------------------------------------------------
__global__ __launch_bounds__(512) void p1_fused(
    const float* __restrict__ q, const bf16* __restrict__ Kimg,
    const bf16* __restrict__ Vimg, const unsigned long long* __restrict__ mbits64,
    float* __restrict__ out, float* __restrict__ attn) {
    __shared__ __align__(16) bf16 Qs[128 * 64];
    __shared__ __align__(16) bf16 KB[2][64 * 64];
    __shared__ __align__(16) bf16 VB[2][64 * 64];

    const int bh   = blockIdx.y;
    const int s0   = blockIdx.x * 128;
    const int b    = bh >> 4;
    const int tid  = threadIdx.x;
    const int w    = tid >> 6;
    const int lane = tid & 63;
    const int col  = lane & 15;
    const int quad = lane >> 4;

    const bf16* kt_base = Kimg + (size_t)bh * 32 * 4096;
    const bf16* vt_base = Vimg + (size_t)bh * 32 * 4096;
    const int soff = tid * 8;          // per-lane source element offset (16B/lane)
    const int doff = w * 512;          // wave-uniform LDS dest element offset

    stage_rowmajor<1024>(q + ((size_t)bh * S + s0) * D, Qs, tid);
    gl16(kt_base + soff, &KB[0][doff]);
    gl16(vt_base + soff, &VB[0][doff]);
    __syncthreads();   // Q + tile 0 resident

    const int ar = w * 16 + col;               // this lane's q-row within block
    bf16x8 aQ0 = *(bf16x8*)(Qs + ar * 64 + swz(ar, quad) * 8);
    bf16x8 aQ1 = *(bf16x8*)(Qs + ar * 64 + swz(ar, 4 + quad) * 8);

    // mask words for this lane's q-row (64-bit word kt covers t = kt*64..+64
    // split lo/hi 32)
    const unsigned long long* mrow =
        mbits64 + (size_t)(b * S + s0 + w * 16 + col) * 32;

    f32x4 oacc[4] = {};
    float lsum = 0.f;

    // ======================= pass 1: out + row sums =======================
    int cur = 0;
    for (int kt = 0; kt < 32; ++kt) {
        const unsigned long long mword = mrow[kt];   // oldest VMEM: waits cheap

        if (kt < 31) {
            gl16(kt_base + (size_t)(kt + 1) * 4096 + soff, &KB[cur ^ 1][doff]);
            gl16(vt_base + (size_t)(kt + 1) * 4096 + soff, &VB[cur ^ 1][doff]);
        }
        const bf16* Kc = KB[cur];
        const bf16* Vc = VB[cur];

        f32x4 sA[4];
#pragma unroll
        for (int ct = 0; ct < 4; ++ct) {
            const int br = ct * 16 + col;      // K row (t block)
            bf16x8 k0 = *(bf16x8*)(Kc + br * 64 + swz(br, quad) * 8);
            bf16x8 k1 = *(bf16x8*)(Kc + br * 64 + swz(br, 4 + quad) * 8);
            __builtin_amdgcn_s_setprio(1);
            f32x4 s = {};
            s = mfma16(k0, aQ0, s);            // swapped: D[t][q], lane: q=col
            s = mfma16(k1, aQ1, s);
            __builtin_amdgcn_s_setprio(0);
            sA[ct] = s;
        }

        const unsigned mlo = (unsigned)mword;
        const unsigned mhi = (unsigned)(mword >> 32);
        bf16x8 aS0, aS1;                       // PV A-fragment, in-lane pack
#pragma unroll
        for (int ct = 0; ct < 4; ++ct) {
            const unsigned mm  = (ct < 2) ? mlo : mhi;
            const int base     = (ct & 1) * 16 + quad * 4;
#pragma unroll
            for (int r = 0; r < 4; ++r) {
                const float sv = ((mm >> (base + r)) & 1u)
                                     ? sA[ct][r] * 0.125f : -1e-12f;
                lsum += __expf(sv);
                const bf16 bs = (bf16)sv;
                if (ct == 0)      aS0[r]     = bs;
                else if (ct == 1) aS0[4 + r] = bs;
                else if (ct == 2) aS1[r]     = bs;
                else              aS1[4 + r] = bs;
            }
        }

        __builtin_amdgcn_s_setprio(1);
#pragma unroll
        for (int dt = 0; dt < 4; ++dt) {
            const int vr = dt * 16 + col;      // Vt row (d)
            bf16x8 v0 = *(bf16x8*)(Vc + vr * 64 + swz(vr, quad) * 8);
            bf16x8 v1 = *(bf16x8*)(Vc + vr * 64 + swz(vr, 4 + quad) * 8);
            oacc[dt] = mfma16(aS0, v0, oacc[dt]);
            oacc[dt] = mfma16(aS1, v1, oacc[dt]);
        }
        __builtin_amdgcn_s_setprio(0);

        __syncthreads();   // next tile resident; all waves done reading cur
        cur ^= 1;
    }

    // ---- out epilogue: rows (s0 + w*16 + quad*4 + r), cols (dt*16 + col) ----
    float* ob = out + ((size_t)bh * S + s0 + w * 16 + quad * 4) * D;
#pragma unroll
    for (int dt = 0; dt < 4; ++dt)
#pragma unroll
        for (int r = 0; r < 4; ++r)
            ob[(size_t)r * D + dt * 16 + col] = oacc[dt][r];

    // ---- rowsum: lanes {col, col+16, col+32, col+48} hold quad-partials ----
    float x = lsum;
    x += __shfl_xor(x, 16);
    x += __shfl_xor(x, 32);
    const float li = 1.0f / x;                 // every lane: linv of row col

    // re-prime K tile 0 for pass 2 (cur is back to 0; KB[0] not in use)
    gl16(kt_base + soff, &KB[0][doff]);
    __syncthreads();

    // ======================= pass 2: attn writes ==========================
    float* arow = attn + ((size_t)bh * S + s0 + w * 16 + col) * (size_t)S;

    cur = 0;
    for (int kt = 0; kt < 32; ++kt) {
        const unsigned long long mword = mrow[kt];
        if (kt < 31)
            gl16(kt_base + (size_t)(kt + 1) * 4096 + soff, &KB[cur ^ 1][doff]);
        const bf16* Kc = KB[cur];

        const unsigned mlo = (unsigned)mword;
        const unsigned mhi = (unsigned)(mword >> 32);
#pragma unroll
        for (int ct = 0; ct < 4; ++ct) {
            const int br = ct * 16 + col;
            bf16x8 k0 = *(bf16x8*)(Kc + br * 64 + swz(br, quad) * 8);
            bf16x8 k1 = *(bf16x8*)(Kc + br * 64 + swz(br, 4 + quad) * 8);
            __builtin_amdgcn_s_setprio(1);
            f32x4 s = {};
            s = mfma16(k0, aQ0, s);
            s = mfma16(k1, aQ1, s);
            __builtin_amdgcn_s_setprio(0);
            const unsigned mm = (ct < 2) ? mlo : mhi;
            const int base    = (ct & 1) * 16 + quad * 4;
            float ev[4];
#pragma unroll
            for (int r = 0; r < 4; ++r) {
                const float sv = ((mm >> (base + r)) & 1u)
                                     ? s[r] * 0.125f : -1e-12f;
                ev[r] = __expf(sv) * li;
            }
            *(float4*)(arow + kt * 64 + ct * 16 + quad * 4) =
                make_float4(ev[0], ev[1], ev[2], ev[3]);
        }

        __syncthreads();
        cur ^= 1;
    }
}

extern "C" void kernel_launch(void* const* d_in, const int* in_sizes, int n_in,
                              void* d_out, int out_size, void* d_ws, size_t ws_size,
                              hipStream_t stream) {
    const float* q     = (const float*)d_in[0];
    const float* k     = (const float*)d_in[1];
    const float* v     = (const float*)d_in[2];
    const int*   masks = (const int*)d_in[3];

    float* out  = (float*)d_out;                 // [2,16,S,D]
    float* attn = out + (size_t)BH * S * D;      // [2,16,S,S]

    // workspace layout (17.25 MiB):
    //   [0, 1 MiB)            mbits
    //   [1.25 MiB, +8 MiB)    Kimg  (bf16 tiled+swizzled)
    //   [9.25 MiB, +8 MiB)    Vimg  (bf16 transposed, tau-permuted, swizzled)
    unsigned* mbits = (unsigned*)d_ws;
    bf16*     Kimg  = (bf16*)((char*)d_ws + (size_t)1048576 + 262144);
    bf16*     Vimg  = (bf16*)((char*)d_ws + (size_t)1048576 + 262144 + 8388608);

    p0_bitpack<<<(2 * S * 64) / 256, 256, 0, stream>>>(masks, mbits);
    p0_kvimg<<<2048, 256, 0, stream>>>(k, v, Kimg, Vimg);

    dim3 g(S / 128, BH);   // x = row-tile (consecutive blocks share bh -> L2 locality)
    p1_fused<<<g, 512, 0, stream>>>(q, Kimg, Vimg,
                                    (const unsigned long long*)mbits, out, attn);
}